// Round 1
// baseline (11031.119 us; speedup 1.0000x reference)
//
#include <hip/hip_runtime.h>
#include <cstdint>
#include <cstddef>

#define NLAYER 2
#define H 2048
#define NH 32
#define NKV 4
#define HD 64
#define FFI 5632
#define SEQ 1024
#define BATCH 2
#define TTOK (BATCH*SEQ)            // 2048 tokens
#define QKVN ((NH + 2*NKV)*HD)      // 2560

typedef float f32x4 __attribute__((ext_vector_type(4)));
typedef __bf16 bf16x8 __attribute__((ext_vector_type(8)));
typedef unsigned short us8 __attribute__((ext_vector_type(8)));

__device__ __forceinline__ unsigned short f2bf(float f) {
    union { float f; unsigned int u; } x; x.f = f;
    unsigned int u = x.u;
    unsigned int r = (u + 0x7fffu + ((u >> 16) & 1u)) >> 16;
    return (unsigned short)r;
}
__device__ __forceinline__ float bf2f(unsigned short b) {
    union { unsigned int u; float f; } x; x.u = ((unsigned int)b) << 16;
    return x.f;
}
// flag-dispatched input load (inputs may be f32 or bf16; probe decides at runtime)
__device__ __forceinline__ float load_in(const void* p, long long i, int bf) {
    return bf ? bf2f(((const unsigned short*)p)[i]) : ((const float*)p)[i];
}

// ---------------- probe: detect whether float inputs are bf16 or f32 ----------------
__global__ void probe_k(const void* embed, int* flag) {
    if (threadIdx.x == 0 && blockIdx.x == 0) {
        const float* e = (const float*)embed;
        int weird = 0;
        for (int i = 0; i < 16; i++) {
            float v = e[i];
            // f32 inputs are N(0,1)*0.02 -> |v| << 1. bf16 pairs misread as f32 are huge.
            if (!(fabsf(v) < 1.0f)) weird++;
        }
        *flag = (weird >= 8) ? 1 : 0;
    }
}

// ---------------- embedding gather ----------------
__global__ __launch_bounds__(256) void gather_k(const int* __restrict__ ids,
        const void* __restrict__ embed, float* __restrict__ resid,
        const int* __restrict__ flagp) {
    int bf = *flagp;
    int t = blockIdx.x;
    long long src = (long long)ids[t] * H;
    long long dst = (long long)t * H;
    for (int i = threadIdx.x; i < H; i += 256)
        resid[dst + i] = load_in(embed, src + i, bf);
}

// ---------------- rmsnorm (optionally writes final output in flag dtype) ----------------
__global__ __launch_bounds__(256) void rmsnorm_k(const float* __restrict__ x,
        const void* __restrict__ w, long long wOff, void* __restrict__ out,
        int finalOut, const int* __restrict__ flagp) {
    int bf = *flagp;
    int t = blockIdx.x;
    const float* xp = x + (long long)t * H;
    float ss = 0.f;
    for (int i = threadIdx.x; i < H; i += 256) { float v = xp[i]; ss += v * v; }
#pragma unroll
    for (int off = 32; off > 0; off >>= 1) ss += __shfl_xor(ss, off);
    __shared__ float red[4];
    if ((threadIdx.x & 63) == 0) red[threadIdx.x >> 6] = ss;
    __syncthreads();
    float scale = rsqrtf((red[0] + red[1] + red[2] + red[3]) / (float)H + 1e-5f);
    long long dst = (long long)t * H;
    for (int i = threadIdx.x; i < H; i += 256) {
        float v = xp[i] * scale * load_in(w, wOff + i, bf);
        if (finalOut && bf) ((unsigned short*)out)[dst + i] = f2bf(v);
        else                ((float*)out)[dst + i] = v;
    }
}

// ---------------- bf16 MFMA GEMM: C[M,N] (+)= A[M,K] @ B[K,N] ----------------
// A: f32 activations. B: external weights (f32 or bf16 per flag), row-major K x N.
// 64x64 tile, BK=32, 4 waves/block, mfma_f32_16x16x32_bf16.
__global__ __launch_bounds__(256) void gemm_k(const float* __restrict__ A,
        const void* __restrict__ B, long long bOff, float* __restrict__ C,
        int M, int N, int K, int addTo, const int* __restrict__ flagp) {
    int bf = *flagp;
    // K-stride padded to 40 (80B): 16B-aligned b128 reads, 2-way bank alias only (free)
    __shared__ __align__(16) unsigned short As[64][40];
    __shared__ __align__(16) unsigned short Bs[64][40];
    int tid = threadIdx.x;
    int wave = tid >> 6, lane = tid & 63;
    int m15 = lane & 15, kq = lane >> 4;
    int row0 = blockIdx.y * 64, col0 = blockIdx.x * 64;
    f32x4 acc[4] = {};
    for (int k0 = 0; k0 < K; k0 += 32) {
        // stage A tile 64x32 (f32 -> bf16)
#pragma unroll
        for (int i = 0; i < 8; i++) {
            int idx = (i << 8) + tid;
            int r = idx >> 5, c = idx & 31;
            As[r][c] = f2bf(A[(long long)(row0 + r) * K + k0 + c]);
        }
        // stage B tile 32x64 transposed -> Bs[n][k]
#pragma unroll
        for (int i = 0; i < 8; i++) {
            int idx = (i << 8) + tid;
            int kk = idx >> 6, n = idx & 63;
            long long off = bOff + (long long)(k0 + kk) * N + col0 + n;
            Bs[n][kk] = bf ? ((const unsigned short*)B)[off]
                           : f2bf(((const float*)B)[off]);
        }
        __syncthreads();
        // A fragment: row m = lane&15, k = (lane>>4)*8 + j (contiguous 8)
        us8 araw = *(const us8*)&As[wave * 16 + m15][kq * 8];
        bf16x8 a = __builtin_bit_cast(bf16x8, araw);
#pragma unroll
        for (int j = 0; j < 4; j++) {
            us8 braw = *(const us8*)&Bs[j * 16 + m15][kq * 8];
            bf16x8 b = __builtin_bit_cast(bf16x8, braw);
            acc[j] = __builtin_amdgcn_mfma_f32_16x16x32_bf16(a, b, acc[j], 0, 0, 0);
        }
        __syncthreads();
    }
    // C/D layout: col = lane&15, row = (lane>>4)*4 + reg
    int rbase = row0 + wave * 16 + kq * 4;
    int cbase = col0 + m15;
#pragma unroll
    for (int j = 0; j < 4; j++) {
#pragma unroll
        for (int r = 0; r < 4; r++) {
            long long off = (long long)(rbase + r) * N + cbase + j * 16;
            if (addTo) C[off] += acc[j][r];
            else       C[off] = acc[j][r];
        }
    }
}

// ---------------- rope + split qkv -> q, k, v buffers ----------------
__global__ __launch_bounds__(256) void rope_k(const float* __restrict__ qkv,
        const int* __restrict__ positions, float* __restrict__ q,
        float* __restrict__ kb, float* __restrict__ vb) {
    int t = blockIdx.x;
    int s = t & (SEQ - 1);
    float pos = (float)positions[s];
    const float* src = qkv + (long long)t * QKVN;
    for (int idx = threadIdx.x; idx < (NH + NKV) * (HD / 2); idx += 256) {
        int hh = idx >> 5;      // head (q heads then kv heads)
        int i  = idx & 31;      // rotary pair index
        float inv = powf(10000.0f, -(float)i / 32.0f);
        float ang = pos * inv;
        float c = cosf(ang), sn = sinf(ang);
        const float* sp; float* dp;
        if (hh < NH) {
            sp = src + hh * HD;
            dp = q + (long long)t * (NH * HD) + hh * HD;
        } else {
            int hk = hh - NH;
            sp = src + NH * HD + hk * HD;
            dp = kb + (long long)t * (NKV * HD) + hk * HD;
        }
        float x1 = sp[i], x2 = sp[i + 32];
        dp[i]      = x1 * c - x2 * sn;
        dp[i + 32] = x2 * c + x1 * sn;
    }
    for (int idx = threadIdx.x; idx < NKV * HD; idx += 256)
        vb[(long long)t * (NKV * HD) + idx] = src[(NH + NKV) * HD + idx];
}

// ---------------- attention: one wave per (b, head, q_row), online softmax ----------------
__global__ __launch_bounds__(256) void attn_k(const float* __restrict__ q,
        const float* __restrict__ kb, const float* __restrict__ vb,
        float* __restrict__ out) {
    int wid = blockIdx.x * 4 + (threadIdx.x >> 6);
    int lane = threadIdx.x & 63;
    int s = wid & (SEQ - 1);
    int h = (wid >> 10) & (NH - 1);
    int b = wid >> 15;
    float qv = q[((long long)(b * SEQ + s)) * (NH * HD) + h * HD + lane];
    int hkv = h >> 3;   // NH/NKV = 8
    const float* kp = kb + (long long)b * SEQ * (NKV * HD) + hkv * HD + lane;
    const float* vp = vb + (long long)b * SEQ * (NKV * HD) + hkv * HD + lane;
    float m = -1e30f, l = 0.f, o = 0.f;
    for (int kk = 0; kk <= s; kk++) {
        float d = qv * kp[kk * (NKV * HD)];
#pragma unroll
        for (int off = 32; off > 0; off >>= 1) d += __shfl_xor(d, off);
        d *= 0.125f;   // HD^-0.5
        float mn = fmaxf(m, d);
        float fac = __expf(m - mn);
        float p = __expf(d - mn);
        l = l * fac + p;
        o = o * fac + p * vp[kk * (NKV * HD)];
        m = mn;
    }
    out[((long long)(b * SEQ + s)) * (NH * HD) + h * HD + lane] = o / l;
}

// ---------------- silu(gate) * up ----------------
__global__ __launch_bounds__(256) void silumul_k(const float* __restrict__ gu,
        float* __restrict__ mid) {
    int i = blockIdx.x * 256 + threadIdx.x;   // total TTOK*FFI = 11.5M, fits int
    int t = i / FFI, j = i - t * FFI;
    float g = gu[(long long)t * (2 * FFI) + j];
    float u = gu[(long long)t * (2 * FFI) + FFI + j];
    mid[i] = g / (1.f + __expf(-g)) * u;
}

extern "C" void kernel_launch(void* const* d_in, const int* in_sizes, int n_in,
                              void* d_out, int out_size, void* d_ws, size_t ws_size,
                              hipStream_t stream) {
    const int*  ids   = (const int*)d_in[0];
    const int*  pos   = (const int*)d_in[1];
    const void* embed = d_in[2];
    const void* wqkv  = d_in[3];
    const void* wo    = d_in[4];
    const void* wgu   = d_in[5];
    const void* wdown = d_in[6];
    const void* ln1   = d_in[7];
    const void* ln2   = d_in[8];
    const void* normw = d_in[9];

    char* ws = (char*)d_ws;
    int* flag = (int*)ws;
    float* base = (float*)(ws + 256);
    const long long T = TTOK;
    float* resid = base;                        // T*H
    float* x     = resid + T * H;               // T*H
    float* sc    = x + T * H;                   // overlapped scratch
    // attention phase carve
    float* qkv  = sc;                           // T*2560
    float* qb   = qkv + T * QKVN;               // T*2048
    float* kb   = qb + T * (NH * HD);           // T*256
    float* vb   = kb + T * (NKV * HD);          // T*256
    float* attn = vb + T * (NKV * HD);          // T*2048
    // ffn phase carve (reuses sc)
    float* gu  = sc;                            // T*11264
    float* mid = gu + T * 2 * FFI;              // T*5632

    probe_k<<<1, 64, 0, stream>>>(embed, flag);
    gather_k<<<TTOK, 256, 0, stream>>>(ids, embed, resid, flag);

    for (int l = 0; l < NLAYER; l++) {
        rmsnorm_k<<<TTOK, 256, 0, stream>>>(resid, ln1, (long long)l * H, x, 0, flag);
        gemm_k<<<dim3(QKVN / 64, TTOK / 64), 256, 0, stream>>>(
            x, wqkv, (long long)l * H * QKVN, qkv, TTOK, QKVN, H, 0, flag);
        rope_k<<<TTOK, 256, 0, stream>>>(qkv, pos, qb, kb, vb);
        attn_k<<<BATCH * NH * SEQ / 4, 256, 0, stream>>>(qb, kb, vb, attn);
        gemm_k<<<dim3(H / 64, TTOK / 64), 256, 0, stream>>>(
            attn, wo, (long long)l * H * H, resid, TTOK, H, H, 1, flag);
        rmsnorm_k<<<TTOK, 256, 0, stream>>>(resid, ln2, (long long)l * H, x, 0, flag);
        gemm_k<<<dim3(2 * FFI / 64, TTOK / 64), 256, 0, stream>>>(
            x, wgu, (long long)l * H * 2 * FFI, gu, TTOK, 2 * FFI, H, 0, flag);
        silumul_k<<<TTOK * FFI / 256, 256, 0, stream>>>(gu, mid);
        gemm_k<<<dim3(H / 64, TTOK / 64), 256, 0, stream>>>(
            mid, wdown, (long long)l * FFI * H, resid, TTOK, H, FFI, 1, flag);
    }
    rmsnorm_k<<<TTOK, 256, 0, stream>>>(resid, normw, 0, d_out, 1, flag);
}

// Round 2
// 6117.328 us; speedup vs baseline: 1.8033x; 1.8033x over previous
//
#include <hip/hip_runtime.h>
#include <cstdint>
#include <cstddef>

#define NLAYER 2
#define H 2048
#define NH 32
#define NKV 4
#define HD 64
#define FFI 5632
#define SEQ 1024
#define BATCH 2
#define TTOK (BATCH*SEQ)            // 2048 tokens
#define QKVN ((NH + 2*NKV)*HD)      // 2560
#define KT 32                       // attention k-tile

typedef float f32x4 __attribute__((ext_vector_type(4)));
typedef __bf16 bf16x8 __attribute__((ext_vector_type(8)));
typedef unsigned short us8 __attribute__((ext_vector_type(8)));

__device__ __forceinline__ unsigned short f2bf(float f) {
    union { float f; unsigned int u; } x; x.f = f;
    unsigned int u = x.u;
    unsigned int r = (u + 0x7fffu + ((u >> 16) & 1u)) >> 16;
    return (unsigned short)r;
}
__device__ __forceinline__ float bf2f(unsigned short b) {
    union { unsigned int u; float f; } x; x.u = ((unsigned int)b) << 16;
    return x.f;
}
// flag-dispatched input load (inputs may be f32 or bf16; probe decides at runtime)
__device__ __forceinline__ float load_in(const void* p, long long i, int bf) {
    return bf ? bf2f(((const unsigned short*)p)[i]) : ((const float*)p)[i];
}

// ---------------- probe: detect whether float inputs are bf16 or f32 ----------------
__global__ void probe_k(const void* embed, int* flag) {
    if (threadIdx.x == 0 && blockIdx.x == 0) {
        const float* e = (const float*)embed;
        int weird = 0;
        for (int i = 0; i < 16; i++) {
            float v = e[i];
            if (!(fabsf(v) < 1.0f)) weird++;
        }
        *flag = (weird >= 8) ? 1 : 0;
    }
}

// ---------------- embedding gather ----------------
__global__ __launch_bounds__(256) void gather_k(const int* __restrict__ ids,
        const void* __restrict__ embed, float* __restrict__ resid,
        const int* __restrict__ flagp) {
    int bf = *flagp;
    int t = blockIdx.x;
    long long src = (long long)ids[t] * H;
    long long dst = (long long)t * H;
    for (int i = threadIdx.x; i < H; i += 256)
        resid[dst + i] = load_in(embed, src + i, bf);
}

// ---------------- rmsnorm ----------------
__global__ __launch_bounds__(256) void rmsnorm_k(const float* __restrict__ x,
        const void* __restrict__ w, long long wOff, void* __restrict__ out,
        int finalOut, const int* __restrict__ flagp) {
    int bf = *flagp;
    int t = blockIdx.x;
    const float* xp = x + (long long)t * H;
    float ss = 0.f;
    for (int i = threadIdx.x; i < H; i += 256) { float v = xp[i]; ss += v * v; }
#pragma unroll
    for (int off = 32; off > 0; off >>= 1) ss += __shfl_xor(ss, off);
    __shared__ float red[4];
    if ((threadIdx.x & 63) == 0) red[threadIdx.x >> 6] = ss;
    __syncthreads();
    float scale = rsqrtf((red[0] + red[1] + red[2] + red[3]) / (float)H + 1e-5f);
    long long dst = (long long)t * H;
    for (int i = threadIdx.x; i < H; i += 256) {
        float v = xp[i] * scale * load_in(w, wOff + i, bf);
        if (finalOut && bf) ((unsigned short*)out)[dst + i] = f2bf(v);
        else                ((float*)out)[dst + i] = v;
    }
}

// ---------------- bf16 MFMA GEMM: C[M,N] (+)= A[M,K] @ B[K,N] ----------------
__global__ __launch_bounds__(256) void gemm_k(const float* __restrict__ A,
        const void* __restrict__ B, long long bOff, float* __restrict__ C,
        int M, int N, int K, int addTo, const int* __restrict__ flagp) {
    int bf = *flagp;
    __shared__ __align__(16) unsigned short As[64][40];
    __shared__ __align__(16) unsigned short Bs[64][40];
    int tid = threadIdx.x;
    int wave = tid >> 6, lane = tid & 63;
    int m15 = lane & 15, kq = lane >> 4;
    int row0 = blockIdx.y * 64, col0 = blockIdx.x * 64;
    f32x4 acc[4] = {};
    for (int k0 = 0; k0 < K; k0 += 32) {
#pragma unroll
        for (int i = 0; i < 8; i++) {
            int idx = (i << 8) + tid;
            int r = idx >> 5, c = idx & 31;
            As[r][c] = f2bf(A[(long long)(row0 + r) * K + k0 + c]);
        }
#pragma unroll
        for (int i = 0; i < 8; i++) {
            int idx = (i << 8) + tid;
            int kk = idx >> 6, n = idx & 63;
            long long off = bOff + (long long)(k0 + kk) * N + col0 + n;
            Bs[n][kk] = bf ? ((const unsigned short*)B)[off]
                           : f2bf(((const float*)B)[off]);
        }
        __syncthreads();
        us8 araw = *(const us8*)&As[wave * 16 + m15][kq * 8];
        bf16x8 a = __builtin_bit_cast(bf16x8, araw);
#pragma unroll
        for (int j = 0; j < 4; j++) {
            us8 braw = *(const us8*)&Bs[j * 16 + m15][kq * 8];
            bf16x8 b = __builtin_bit_cast(bf16x8, braw);
            acc[j] = __builtin_amdgcn_mfma_f32_16x16x32_bf16(a, b, acc[j], 0, 0, 0);
        }
        __syncthreads();
    }
    int rbase = row0 + wave * 16 + kq * 4;
    int cbase = col0 + m15;
#pragma unroll
    for (int j = 0; j < 4; j++) {
#pragma unroll
        for (int r = 0; r < 4; r++) {
            long long off = (long long)(rbase + r) * N + cbase + j * 16;
            if (addTo) C[off] += acc[j][r];
            else       C[off] = acc[j][r];
        }
    }
}

// ---------------- rope + split qkv -> q, k (roped), vT ----------------
// vT layout: [(b*NKV + hkv)*HD + d][SEQ]  (pre-transposed for attention staging)
__global__ __launch_bounds__(256) void rope_k(const float* __restrict__ qkv,
        const int* __restrict__ positions, float* __restrict__ q,
        float* __restrict__ kb, float* __restrict__ vT) {
    int t = blockIdx.x;
    int s = t & (SEQ - 1);
    int b = t >> 10;
    float pos = (float)positions[s];
    const float* src = qkv + (long long)t * QKVN;
    for (int idx = threadIdx.x; idx < (NH + NKV) * (HD / 2); idx += 256) {
        int hh = idx >> 5;      // head (q heads then kv heads)
        int i  = idx & 31;      // rotary pair index
        float inv = powf(10000.0f, -(float)i / 32.0f);
        float ang = pos * inv;
        float c = cosf(ang), sn = sinf(ang);
        const float* sp; float* dp;
        if (hh < NH) {
            sp = src + hh * HD;
            dp = q + (long long)t * (NH * HD) + hh * HD;
        } else {
            int hk = hh - NH;
            sp = src + NH * HD + hk * HD;
            dp = kb + (long long)t * (NKV * HD) + hk * HD;
        }
        float x1 = sp[i], x2 = sp[i + 32];
        dp[i]      = x1 * c - x2 * sn;
        dp[i + 32] = x2 * c + x1 * sn;
    }
    for (int idx = threadIdx.x; idx < NKV * HD; idx += 256) {
        int hkv = idx >> 6, d = idx & 63;
        vT[((long long)((b * NKV + hkv) * HD + d)) * SEQ + s] = src[(NH + NKV) * HD + idx];
    }
}

// ---------------- flash attention, MFMA 16x16x32 bf16 ----------------
// grid (SEQ/64, NH, BATCH), 4 waves/block; wave owns 16 q rows.
__global__ __launch_bounds__(256) void fattn_k(const float* __restrict__ qb,
        const float* __restrict__ kb, const float* __restrict__ vT,
        float* __restrict__ out) {
    int qt = blockIdx.x, h = blockIdx.y, b = blockIdx.z;
    int q0 = qt * 64;
    int hkv = h >> 3;                        // NH/NKV = 8
    int tid = threadIdx.x, wave = tid >> 6, lane = tid & 63;
    int m15 = lane & 15, quad = lane >> 4;

    __shared__ __align__(16) unsigned short Qs[64][72];
    __shared__ __align__(16) unsigned short Ks[KT][72];
    __shared__ __align__(16) unsigned short Vt[64][40];
    __shared__ __align__(16) unsigned short Ps[4][16][40];

    // stage Q tile 64x64 (scaled by HD^-0.5)
#pragma unroll
    for (int i = 0; i < 16; i++) {
        int idx = i * 256 + tid;
        int r = idx >> 6, c = idx & 63;
        Qs[r][c] = f2bf(qb[((long long)(b * SEQ + q0 + r)) * (NH * HD) + h * HD + c] * 0.125f);
    }
    __syncthreads();
    bf16x8 qf0, qf1;
    {
        us8 r0 = *(const us8*)&Qs[wave * 16 + m15][quad * 8];
        us8 r1 = *(const us8*)&Qs[wave * 16 + m15][32 + quad * 8];
        qf0 = __builtin_bit_cast(bf16x8, r0);
        qf1 = __builtin_bit_cast(bf16x8, r1);
    }

    f32x4 acc[4] = {};              // O, C-layout: col=g*16+m15 (hd), row=quad*4+r
    float mrow[4], lrow[4];
#pragma unroll
    for (int r = 0; r < 4; r++) { mrow[r] = -1e30f; lrow[r] = 0.f; }

    int qrow = q0 + wave * 16 + quad * 4;    // + r
    int ktiles = q0 / KT + 2;
    for (int it = 0; it < ktiles; it++) {
        int kt0 = it * KT;
        __syncthreads();
        // stage K tile: Ks[kpos][hd] (exactly B-frag layout for QK^T)
        {
            int d = tid & 63, kkb = tid >> 6;
#pragma unroll
            for (int i = 0; i < 8; i++) {
                int kk = kkb + i * 4;
                Ks[kk][d] = f2bf(kb[((long long)(b * SEQ + kt0 + kk)) * (NKV * HD) + hkv * HD + d]);
            }
        }
        // stage V^T tile: Vt[hd][kpos] from pre-transposed global
        {
            int kk = tid & 31, db = tid >> 5;
#pragma unroll
            for (int i = 0; i < 8; i++) {
                int d = db + i * 8;
                Vt[d][kk] = f2bf(vT[((long long)((b * NKV + hkv) * HD + d)) * SEQ + kt0 + kk]);
            }
        }
        __syncthreads();
        // S = Q K^T (16 q rows x 32 kpos per wave)
        f32x4 s[2] = {};
#pragma unroll
        for (int g = 0; g < 2; g++) {
            us8 b0 = *(const us8*)&Ks[g * 16 + m15][quad * 8];
            us8 b1 = *(const us8*)&Ks[g * 16 + m15][32 + quad * 8];
            s[g] = __builtin_amdgcn_mfma_f32_16x16x32_bf16(qf0, __builtin_bit_cast(bf16x8, b0), s[g], 0, 0, 0);
            s[g] = __builtin_amdgcn_mfma_f32_16x16x32_bf16(qf1, __builtin_bit_cast(bf16x8, b1), s[g], 0, 0, 0);
        }
        // causal mask
#pragma unroll
        for (int g = 0; g < 2; g++) {
            int kpos = kt0 + g * 16 + m15;
#pragma unroll
            for (int r = 0; r < 4; r++)
                if (kpos > qrow + r) s[g][r] = -1e30f;
        }
        // online softmax (stats per row, quad-local shuffle reduce)
        float p0[4], p1[4], alpha[4];
#pragma unroll
        for (int r = 0; r < 4; r++) {
            float mx = fmaxf(s[0][r], s[1][r]);
#pragma unroll
            for (int off = 1; off < 16; off <<= 1) mx = fmaxf(mx, __shfl_xor(mx, off));
            float mn = fmaxf(mrow[r], mx);
            alpha[r] = __expf(mrow[r] - mn);
            mrow[r] = mn;
            p0[r] = __expf(s[0][r] - mn);
            p1[r] = __expf(s[1][r] - mn);
            float ps = p0[r] + p1[r];
#pragma unroll
            for (int off = 1; off < 16; off <<= 1) ps += __shfl_xor(ps, off);
            lrow[r] = lrow[r] * alpha[r] + ps;
        }
        // P: C-layout -> A-layout via wave-private LDS patch
#pragma unroll
        for (int r = 0; r < 4; r++) {
            Ps[wave][quad * 4 + r][m15]      = f2bf(p0[r]);
            Ps[wave][quad * 4 + r][16 + m15] = f2bf(p1[r]);
        }
        us8 praw = *(const us8*)&Ps[wave][m15][quad * 8];
        bf16x8 pf = __builtin_bit_cast(bf16x8, praw);
        // O = O*alpha + P @ V
#pragma unroll
        for (int g = 0; g < 4; g++) {
#pragma unroll
            for (int r = 0; r < 4; r++) acc[g][r] *= alpha[r];
            us8 vraw = *(const us8*)&Vt[g * 16 + m15][quad * 8];
            acc[g] = __builtin_amdgcn_mfma_f32_16x16x32_bf16(pf, __builtin_bit_cast(bf16x8, vraw), acc[g], 0, 0, 0);
        }
    }
    // epilogue
#pragma unroll
    for (int g = 0; g < 4; g++) {
#pragma unroll
        for (int r = 0; r < 4; r++) {
            long long off = ((long long)(b * SEQ + q0 + wave * 16 + quad * 4 + r)) * (NH * HD)
                            + h * HD + g * 16 + m15;
            out[off] = acc[g][r] / lrow[r];
        }
    }
}

// ---------------- silu(gate) * up ----------------
__global__ __launch_bounds__(256) void silumul_k(const float* __restrict__ gu,
        float* __restrict__ mid) {
    int i = blockIdx.x * 256 + threadIdx.x;
    int t = i / FFI, j = i - t * FFI;
    float g = gu[(long long)t * (2 * FFI) + j];
    float u = gu[(long long)t * (2 * FFI) + FFI + j];
    mid[i] = g / (1.f + __expf(-g)) * u;
}

extern "C" void kernel_launch(void* const* d_in, const int* in_sizes, int n_in,
                              void* d_out, int out_size, void* d_ws, size_t ws_size,
                              hipStream_t stream) {
    const int*  ids   = (const int*)d_in[0];
    const int*  pos   = (const int*)d_in[1];
    const void* embed = d_in[2];
    const void* wqkv  = d_in[3];
    const void* wo    = d_in[4];
    const void* wgu   = d_in[5];
    const void* wdown = d_in[6];
    const void* ln1   = d_in[7];
    const void* ln2   = d_in[8];
    const void* normw = d_in[9];

    char* ws = (char*)d_ws;
    int* flag = (int*)ws;
    float* base = (float*)(ws + 256);
    const long long T = TTOK;
    float* resid = base;                        // T*H
    float* x     = resid + T * H;               // T*H
    float* sc    = x + T * H;                   // overlapped scratch
    // attention phase carve
    float* qkv  = sc;                           // T*2560
    float* qb   = qkv + T * QKVN;               // T*2048
    float* kb   = qb + T * (NH * HD);           // T*256
    float* vT   = kb + T * (NKV * HD);          // T*256 (transposed layout)
    float* attn = vT + T * (NKV * HD);          // T*2048
    // ffn phase carve (reuses sc)
    float* gu  = sc;                            // T*11264
    float* mid = gu + T * 2 * FFI;              // T*5632

    probe_k<<<1, 64, 0, stream>>>(embed, flag);
    gather_k<<<TTOK, 256, 0, stream>>>(ids, embed, resid, flag);

    for (int l = 0; l < NLAYER; l++) {
        rmsnorm_k<<<TTOK, 256, 0, stream>>>(resid, ln1, (long long)l * H, x, 0, flag);
        gemm_k<<<dim3(QKVN / 64, TTOK / 64), 256, 0, stream>>>(
            x, wqkv, (long long)l * H * QKVN, qkv, TTOK, QKVN, H, 0, flag);
        rope_k<<<TTOK, 256, 0, stream>>>(qkv, pos, qb, kb, vT);
        fattn_k<<<dim3(SEQ / 64, NH, BATCH), 256, 0, stream>>>(qb, kb, vT, attn);
        gemm_k<<<dim3(H / 64, TTOK / 64), 256, 0, stream>>>(
            attn, wo, (long long)l * H * H, resid, TTOK, H, H, 1, flag);
        rmsnorm_k<<<TTOK, 256, 0, stream>>>(resid, ln2, (long long)l * H, x, 0, flag);
        gemm_k<<<dim3(2 * FFI / 64, TTOK / 64), 256, 0, stream>>>(
            x, wgu, (long long)l * H * 2 * FFI, gu, TTOK, 2 * FFI, H, 0, flag);
        silumul_k<<<TTOK * FFI / 256, 256, 0, stream>>>(gu, mid);
        gemm_k<<<dim3(H / 64, TTOK / 64), 256, 0, stream>>>(
            mid, wdown, (long long)l * FFI * H, resid, TTOK, H, FFI, 1, flag);
    }
    rmsnorm_k<<<TTOK, 256, 0, stream>>>(resid, normw, 0, d_out, 1, flag);
}

// Round 3
// 1715.555 us; speedup vs baseline: 6.4301x; 3.5658x over previous
//
#include <hip/hip_runtime.h>
#include <cstdint>
#include <cstddef>

#define NLAYER 2
#define H 2048
#define NH 32
#define NKV 4
#define HD 64
#define FFI 5632
#define SEQ 1024
#define BATCH 2
#define TTOK (BATCH*SEQ)            // 2048 tokens
#define QKVN ((NH + 2*NKV)*HD)      // 2560
#define KT 32                       // attention k-tile

typedef float f32x4 __attribute__((ext_vector_type(4)));
typedef __bf16 bf16x8 __attribute__((ext_vector_type(8)));
typedef unsigned short us8 __attribute__((ext_vector_type(8)));
typedef unsigned short us4 __attribute__((ext_vector_type(4)));
typedef unsigned short us_t;

__device__ __forceinline__ unsigned short f2bf(float f) {
    union { float f; unsigned int u; } x; x.f = f;
    unsigned int u = x.u;
    unsigned int r = (u + 0x7fffu + ((u >> 16) & 1u)) >> 16;
    return (unsigned short)r;
}
__device__ __forceinline__ float bf2f(unsigned short b) {
    union { unsigned int u; float f; } x; x.u = ((unsigned int)b) << 16;
    return x.f;
}
__device__ __forceinline__ float load_in(const void* p, long long i, int bf) {
    return bf ? bf2f(((const unsigned short*)p)[i]) : ((const float*)p)[i];
}
// async global->LDS, 16B per lane. HW dest = wave-uniform base + lane*16.
__device__ __forceinline__ void async16(const void* g, void* l) {
    __builtin_amdgcn_global_load_lds(
        (const __attribute__((address_space(1))) void*)g,
        (__attribute__((address_space(3))) void*)l, 16, 0, 0);
}

// ---------------- probe: detect whether float inputs are bf16 or f32 ----------------
__global__ void probe_k(const void* embed, int* flag) {
    if (threadIdx.x == 0 && blockIdx.x == 0) {
        const float* e = (const float*)embed;
        int weird = 0;
        for (int i = 0; i < 16; i++) {
            float v = e[i];
            if (!(fabsf(v) < 1.0f)) weird++;
        }
        *flag = (weird >= 8) ? 1 : 0;
    }
}

// ---------------- embedding gather ----------------
__global__ __launch_bounds__(256) void gather_k(const int* __restrict__ ids,
        const void* __restrict__ embed, float* __restrict__ resid,
        const int* __restrict__ flagp) {
    int bf = *flagp;
    int t = blockIdx.x;
    long long src = (long long)ids[t] * H;
    long long dst = (long long)t * H;
    for (int i = threadIdx.x; i < H; i += 256)
        resid[dst + i] = load_in(embed, src + i, bf);
}

// ---------------- rmsnorm: resid f32 -> bf16 x (or final out in flag dtype) ----------------
__global__ __launch_bounds__(256) void rmsnorm_k(const float* __restrict__ x,
        const void* __restrict__ w, long long wOff, void* __restrict__ out,
        int finalOut, const int* __restrict__ flagp) {
    int bf = *flagp;
    int t = blockIdx.x;
    const float* xp = x + (long long)t * H;
    float ss = 0.f;
    for (int i = threadIdx.x; i < H; i += 256) { float v = xp[i]; ss += v * v; }
#pragma unroll
    for (int off = 32; off > 0; off >>= 1) ss += __shfl_xor(ss, off);
    __shared__ float red[4];
    if ((threadIdx.x & 63) == 0) red[threadIdx.x >> 6] = ss;
    __syncthreads();
    float scale = rsqrtf((red[0] + red[1] + red[2] + red[3]) / (float)H + 1e-5f);
    long long dst = (long long)t * H;
    for (int i = threadIdx.x; i < H; i += 256) {
        float v = xp[i] * scale * load_in(w, wOff + i, bf);
        if (!finalOut)      ((unsigned short*)out)[dst + i] = f2bf(v);
        else if (bf)        ((unsigned short*)out)[dst + i] = f2bf(v);
        else                ((float*)out)[dst + i] = v;
    }
}

// ---------------- weight transpose+cast: W[k][n] (flag dtype) -> Wt[n][k] bf16 ----------------
__global__ __launch_bounds__(256) void transpose_k(const void* __restrict__ W, long long wOff,
        unsigned short* __restrict__ Wt, int K, int N, const int* __restrict__ flagp) {
    int bf = *flagp;
    __shared__ float Ts[64][65];
    int n0 = blockIdx.x * 64, k0 = blockIdx.y * 64;
    int c = threadIdx.x & 63, rb = threadIdx.x >> 6;
#pragma unroll
    for (int i = 0; i < 16; i++) {
        int r = rb * 16 + i;
        Ts[r][c] = load_in(W, wOff + (long long)(k0 + r) * N + n0 + c, bf);
    }
    __syncthreads();
    int kk = threadIdx.x & 63, cb = threadIdx.x >> 6;
#pragma unroll
    for (int i = 0; i < 16; i++) {
        int nn = cb * 16 + i;
        Wt[(long long)(n0 + nn) * K + k0 + kk] = f2bf(Ts[kk][nn]);
    }
}

// ---------------- m97-style bf16 GEMM: C[M,*] = A[M,K] @ Bt[N,K]^T ----------------
// 128x128 tile, BK=32, 4 waves (2x2 of 64x64), global_load_lds staging.
// mode: 0 = f32 store, 1 = f32 +=, 2 = bf16 store
__global__ __launch_bounds__(256) void gemm_bt(const unsigned short* __restrict__ A,
        const unsigned short* __restrict__ Bt, void* __restrict__ C,
        int K, int ldc, int mode) {
    __shared__ __align__(16) unsigned short As[128 * 32];
    __shared__ __align__(16) unsigned short Bs[128 * 32];
    int tid = threadIdx.x, wave = tid >> 6, lane = tid & 63;
    int m15 = lane & 15, quad = lane >> 4;
    int row0 = blockIdx.y * 128, col0 = blockIdx.x * 128;
    int wr = (wave >> 1) * 64, wc = (wave & 1) * 64;
    int srow = lane >> 2, scol = (lane & 3) * 8;
    const unsigned short* Ag = A + (long long)(row0 + wave * 32 + srow) * K + scol;
    const unsigned short* Bg = Bt + (long long)(col0 + wave * 32 + srow) * K + scol;
    unsigned short* Al = As + wave * 32 * 32 + lane * 8;
    unsigned short* Bl = Bs + wave * 32 * 32 + lane * 8;
    f32x4 acc[4][4] = {};
    for (int k0 = 0; k0 < K; k0 += 32) {
        __syncthreads();
        async16(Ag + k0, Al);
        async16(Ag + (long long)16 * K + k0, Al + 16 * 32);
        async16(Bg + k0, Bl);
        async16(Bg + (long long)16 * K + k0, Bl + 16 * 32);
        __syncthreads();
        bf16x8 af[4], bff[4];
#pragma unroll
        for (int i = 0; i < 4; i++) {
            af[i]  = __builtin_bit_cast(bf16x8, *(const us8*)&As[(wr + i * 16 + m15) * 32 + quad * 8]);
            bff[i] = __builtin_bit_cast(bf16x8, *(const us8*)&Bs[(wc + i * 16 + m15) * 32 + quad * 8]);
        }
#pragma unroll
        for (int i = 0; i < 4; i++)
#pragma unroll
            for (int j = 0; j < 4; j++)
                acc[i][j] = __builtin_amdgcn_mfma_f32_16x16x32_bf16(af[i], bff[j], acc[i][j], 0, 0, 0);
    }
    int rb = row0 + wr + quad * 4, cb = col0 + wc + m15;
#pragma unroll
    for (int i = 0; i < 4; i++)
#pragma unroll
        for (int j = 0; j < 4; j++)
#pragma unroll
            for (int r = 0; r < 4; r++) {
                long long off = (long long)(rb + i * 16 + r) * ldc + cb + j * 16;
                if (mode == 1)      ((float*)C)[off] += acc[i][j][r];
                else if (mode == 2) ((unsigned short*)C)[off] = f2bf(acc[i][j][r]);
                else                ((float*)C)[off] = acc[i][j][r];
            }
}

// ---------------- rope: qkv bf16 -> qb (scaled 0.125), kb, vT (all bf16) ----------------
__global__ __launch_bounds__(256) void rope_k(const unsigned short* __restrict__ qkv,
        const int* __restrict__ positions, unsigned short* __restrict__ qb,
        unsigned short* __restrict__ kb, unsigned short* __restrict__ vT) {
    int t = blockIdx.x;
    int s = t & (SEQ - 1);
    int b = t >> 10;
    float pos = (float)positions[s];
    const unsigned short* src = qkv + (long long)t * QKVN;
    for (int idx = threadIdx.x; idx < (NH + NKV) * (HD / 2); idx += 256) {
        int hh = idx >> 5;
        int i  = idx & 31;
        float inv = powf(10000.0f, -(float)i / 32.0f);
        float ang = pos * inv;
        float c = cosf(ang), sn = sinf(ang);
        const unsigned short* sp; unsigned short* dp; float scale;
        if (hh < NH) {
            sp = src + hh * HD;
            dp = qb + (long long)t * (NH * HD) + hh * HD;
            scale = 0.125f;                      // HD^-0.5 folded into Q
        } else {
            int hk = hh - NH;
            sp = src + NH * HD + hk * HD;
            dp = kb + (long long)t * (NKV * HD) + hk * HD;
            scale = 1.0f;
        }
        float x1 = bf2f(sp[i]), x2 = bf2f(sp[i + 32]);
        dp[i]      = f2bf((x1 * c - x2 * sn) * scale);
        dp[i + 32] = f2bf((x2 * c + x1 * sn) * scale);
    }
    for (int idx = threadIdx.x; idx < NKV * HD; idx += 256) {
        int hkv = idx >> 6, d = idx & 63;
        vT[((long long)((b * NKV + hkv) * HD + d)) * SEQ + s] = src[(NH + NKV) * HD + idx];
    }
}

// ---------------- flash attention, MFMA 16x16x32 bf16, all-bf16 I/O ----------------
__global__ __launch_bounds__(256) void fattn_k(const unsigned short* __restrict__ qb,
        const unsigned short* __restrict__ kb, const unsigned short* __restrict__ vT,
        unsigned short* __restrict__ out) {
    int qt = blockIdx.x, h = blockIdx.y, b = blockIdx.z;
    int q0 = qt * 64;
    int hkv = h >> 3;
    int tid = threadIdx.x, wave = tid >> 6, lane = tid & 63;
    int m15 = lane & 15, quad = lane >> 4;

    __shared__ __align__(16) unsigned short Qs[64][72];
    __shared__ __align__(16) unsigned short Ks[KT][72];
    __shared__ __align__(16) unsigned short Vt[64][40];
    __shared__ __align__(16) unsigned short Ps[4][16][40];

    {   // stage Q 64x64 (already scaled in rope)
        int r = tid >> 4, c4 = (tid & 15) * 4;
#pragma unroll
        for (int i = 0; i < 4; i++) {
            int row = r + i * 16;
            *(us4*)&Qs[row][c4] =
                *(const us4*)&qb[((long long)(b * SEQ + q0 + row)) * (NH * HD) + h * HD + c4];
        }
    }
    __syncthreads();
    bf16x8 qf0, qf1;
    {
        us8 r0 = *(const us8*)&Qs[wave * 16 + m15][quad * 8];
        us8 r1 = *(const us8*)&Qs[wave * 16 + m15][32 + quad * 8];
        qf0 = __builtin_bit_cast(bf16x8, r0);
        qf1 = __builtin_bit_cast(bf16x8, r1);
    }

    f32x4 acc[4] = {};
    float mrow[4], lrow[4];
#pragma unroll
    for (int r = 0; r < 4; r++) { mrow[r] = -1e30f; lrow[r] = 0.f; }

    int qrow = q0 + wave * 16 + quad * 4;
    int ktiles = q0 / KT + 2;
    for (int it = 0; it < ktiles; it++) {
        int kt0 = it * KT;
        __syncthreads();
        {   // K tile: Ks[kpos][hd]
            int kk = tid >> 4, c4 = (tid & 15) * 4;
#pragma unroll
            for (int i = 0; i < 2; i++) {
                int k = kk + i * 16;
                *(us4*)&Ks[k][c4] =
                    *(const us4*)&kb[((long long)(b * SEQ + kt0 + k)) * (NKV * HD) + hkv * HD + c4];
            }
        }
        {   // V^T tile: Vt[hd][kpos]
            int d = tid >> 3, k4 = (tid & 7) * 4;
#pragma unroll
            for (int i = 0; i < 2; i++) {
                int dd = d + i * 32;
                *(us4*)&Vt[dd][k4] =
                    *(const us4*)&vT[((long long)((b * NKV + hkv) * HD + dd)) * SEQ + kt0 + k4];
            }
        }
        __syncthreads();
        f32x4 s[2] = {};
#pragma unroll
        for (int g = 0; g < 2; g++) {
            us8 b0 = *(const us8*)&Ks[g * 16 + m15][quad * 8];
            us8 b1 = *(const us8*)&Ks[g * 16 + m15][32 + quad * 8];
            s[g] = __builtin_amdgcn_mfma_f32_16x16x32_bf16(qf0, __builtin_bit_cast(bf16x8, b0), s[g], 0, 0, 0);
            s[g] = __builtin_amdgcn_mfma_f32_16x16x32_bf16(qf1, __builtin_bit_cast(bf16x8, b1), s[g], 0, 0, 0);
        }
#pragma unroll
        for (int g = 0; g < 2; g++) {
            int kpos = kt0 + g * 16 + m15;
#pragma unroll
            for (int r = 0; r < 4; r++)
                if (kpos > qrow + r) s[g][r] = -1e30f;
        }
        float p0[4], p1[4], alpha[4];
#pragma unroll
        for (int r = 0; r < 4; r++) {
            float mx = fmaxf(s[0][r], s[1][r]);
#pragma unroll
            for (int off = 1; off < 16; off <<= 1) mx = fmaxf(mx, __shfl_xor(mx, off));
            float mn = fmaxf(mrow[r], mx);
            alpha[r] = __expf(mrow[r] - mn);
            mrow[r] = mn;
            p0[r] = __expf(s[0][r] - mn);
            p1[r] = __expf(s[1][r] - mn);
            float ps = p0[r] + p1[r];
#pragma unroll
            for (int off = 1; off < 16; off <<= 1) ps += __shfl_xor(ps, off);
            lrow[r] = lrow[r] * alpha[r] + ps;
        }
#pragma unroll
        for (int r = 0; r < 4; r++) {
            Ps[wave][quad * 4 + r][m15]      = f2bf(p0[r]);
            Ps[wave][quad * 4 + r][16 + m15] = f2bf(p1[r]);
        }
        us8 praw = *(const us8*)&Ps[wave][m15][quad * 8];
        bf16x8 pf = __builtin_bit_cast(bf16x8, praw);
#pragma unroll
        for (int g = 0; g < 4; g++) {
#pragma unroll
            for (int r = 0; r < 4; r++) acc[g][r] *= alpha[r];
            us8 vraw = *(const us8*)&Vt[g * 16 + m15][quad * 8];
            acc[g] = __builtin_amdgcn_mfma_f32_16x16x32_bf16(pf, __builtin_bit_cast(bf16x8, vraw), acc[g], 0, 0, 0);
        }
    }
#pragma unroll
    for (int g = 0; g < 4; g++) {
#pragma unroll
        for (int r = 0; r < 4; r++) {
            long long off = ((long long)(b * SEQ + q0 + wave * 16 + quad * 4 + r)) * (NH * HD)
                            + h * HD + g * 16 + m15;
            out[off] = f2bf(acc[g][r] / lrow[r]);
        }
    }
}

// ---------------- silu(gate)*up, in place into gate ----------------
__global__ __launch_bounds__(256) void silumul_k(unsigned short* __restrict__ gate,
        const unsigned short* __restrict__ up) {
    long long i = (long long)blockIdx.x * 256 + threadIdx.x;
    float g = bf2f(gate[i]), u = bf2f(up[i]);
    gate[i] = f2bf(g / (1.f + __expf(-g)) * u);
}

extern "C" void kernel_launch(void* const* d_in, const int* in_sizes, int n_in,
                              void* d_out, int out_size, void* d_ws, size_t ws_size,
                              hipStream_t stream) {
    const int*  ids   = (const int*)d_in[0];
    const int*  pos   = (const int*)d_in[1];
    const void* embed = d_in[2];
    const void* wqkv  = d_in[3];
    const void* wo    = d_in[4];
    const void* wgu   = d_in[5];
    const void* wdown = d_in[6];
    const void* ln1   = d_in[7];
    const void* ln2   = d_in[8];
    const void* normw = d_in[9];

    char* p = (char*)d_ws;
    int* flag = (int*)p;                         p += 256;
    us_t* wqkvT  = (us_t*)p;                     p += (size_t)QKVN * H * 2;        // 10.5 MB
    us_t* woT    = (us_t*)p;                     p += (size_t)H * H * 2;           // 8.4 MB
    us_t* wguT   = (us_t*)p;                     p += (size_t)2 * FFI * H * 2;     // 46.1 MB
    us_t* wdownT = (us_t*)p;                     p += (size_t)H * FFI * 2;         // 23.1 MB
    float* resid = (float*)p;                    p += (size_t)TTOK * H * 4;        // 16.8 MB
    us_t* x      = (us_t*)p;                     p += (size_t)TTOK * H * 2;        // 8.4 MB
    us_t* S      = (us_t*)p;                     // 46.1 MB scratch union
    // phase A (attention) carve inside S
    us_t* qkv  = S;                               // TTOK*2560
    us_t* qb   = qkv + (size_t)TTOK * QKVN;       // TTOK*2048
    us_t* kb   = qb + (size_t)TTOK * NH * HD;     // TTOK*256
    us_t* vT   = kb + (size_t)TTOK * NKV * HD;    // TTOK*256
    us_t* attn = vT + (size_t)TTOK * NKV * HD;    // TTOK*2048
    // phase B (ffn) carve inside S
    us_t* gate = S;                               // TTOK*FFI
    us_t* up   = S + (size_t)TTOK * FFI;          // TTOK*FFI

    probe_k<<<1, 64, 0, stream>>>(embed, flag);
    gather_k<<<TTOK, 256, 0, stream>>>(ids, embed, resid, flag);

    for (int l = 0; l < NLAYER; l++) {
        // per-layer weight transpose+cast to bf16 [n][k]
        transpose_k<<<dim3(QKVN / 64, H / 64), 256, 0, stream>>>(
            wqkv, (long long)l * H * QKVN, wqkvT, H, QKVN, flag);
        transpose_k<<<dim3(H / 64, H / 64), 256, 0, stream>>>(
            wo, (long long)l * H * H, woT, H, H, flag);
        transpose_k<<<dim3(2 * FFI / 64, H / 64), 256, 0, stream>>>(
            wgu, (long long)l * H * 2 * FFI, wguT, H, 2 * FFI, flag);
        transpose_k<<<dim3(H / 64, FFI / 64), 256, 0, stream>>>(
            wdown, (long long)l * FFI * H, wdownT, FFI, H, flag);

        rmsnorm_k<<<TTOK, 256, 0, stream>>>(resid, ln1, (long long)l * H, x, 0, flag);
        gemm_bt<<<dim3(QKVN / 128, TTOK / 128), 256, 0, stream>>>(
            x, wqkvT, qkv, H, QKVN, 2);
        rope_k<<<TTOK, 256, 0, stream>>>(qkv, pos, qb, kb, vT);
        fattn_k<<<dim3(SEQ / 64, NH, BATCH), 256, 0, stream>>>(qb, kb, vT, attn);
        gemm_bt<<<dim3(H / 128, TTOK / 128), 256, 0, stream>>>(
            attn, woT, resid, H, H, 1);
        rmsnorm_k<<<TTOK, 256, 0, stream>>>(resid, ln2, (long long)l * H, x, 0, flag);
        gemm_bt<<<dim3(FFI / 128, TTOK / 128), 256, 0, stream>>>(
            x, wguT, gate, H, FFI, 2);
        gemm_bt<<<dim3(FFI / 128, TTOK / 128), 256, 0, stream>>>(
            x, wguT + (size_t)FFI * H, up, H, FFI, 2);
        silumul_k<<<(int)(((long long)TTOK * FFI) / 256), 256, 0, stream>>>(gate, up);
        gemm_bt<<<dim3(H / 128, TTOK / 128), 256, 0, stream>>>(
            gate, wdownT, resid, FFI, H, 1);
    }
    rmsnorm_k<<<TTOK, 256, 0, stream>>>(resid, normw, 0, d_out, 1, flag);
}